// Round 2
// baseline (7841.273 us; speedup 1.0000x reference)
//
#include <hip/hip_runtime.h>
#include <math.h>

// Seq2Seq semantic parser w/ attention — round 2.
// bf16 MFMA for all GEMM-shaped work, fp32 state/gates/softmax.
// Changes vs r1: bf16 P + bf16 ENC (ws 307->210MB, attn traffic halved),
// XCD-bijective swizzle in gemm_k, templated gemm output dtype.
// B=64 T=128 OUT=64 E=256 H=512 V=20000.

#define B_   64
#define T_   128
#define OUT_ 64
#define E_   256
#define H_   512
#define V_   20000
#define G4_  2048   // 4H
#define H2_  1024   // 2H
#define CAT_ 1536   // 3H

typedef float f32x4 __attribute__((ext_vector_type(4)));
typedef short bf16x8 __attribute__((ext_vector_type(8)));
typedef short short4v __attribute__((ext_vector_type(4)));

__device__ __forceinline__ short f2bf(float f) {
  unsigned u = __builtin_bit_cast(unsigned, f);
  u = (u + 0x7fff + ((u >> 16) & 1)) >> 16;   // RNE
  return (short)u;
}
__device__ __forceinline__ float bf2f(short s) {
  unsigned u = ((unsigned)(unsigned short)s) << 16;
  return __builtin_bit_cast(float, u);
}
__device__ __forceinline__ float sigm(float x) { return 1.f / (1.f + expf(-x)); }

__device__ __forceinline__ void gload16(const void* g, void* l) {
  __builtin_amdgcn_global_load_lds((const __attribute__((address_space(1))) void*)g,
                                   (__attribute__((address_space(3))) void*)l, 16, 0, 0);
}
__device__ __forceinline__ f32x4 mfma16(bf16x8 a, bf16x8 b, f32x4 c) {
  return __builtin_amdgcn_mfma_f32_16x16x32_bf16(a, b, c, 0, 0, 0);
}

// ---------------- generic bf16 GEMM:  C[M,N] = A[M,K] * Bm[N,K]^T (+bias) ----------------
// tile 128x128, BK=64, 4 waves 2x2 of 64x64, m97-style global_load_lds staging.
// M = gridDim.y*128 (must divide); N tail handled by clamp+guard.
// OB=true -> bf16 output, else fp32. XCD-bijective swizzle (requires nwg%8==0).
template<bool OB>
__global__ void __launch_bounds__(256) gemm_k(const short* __restrict__ A,
                                              const short* __restrict__ Bm,
                                              void* __restrict__ Cv,
                                              const float* __restrict__ bias,
                                              int N, int K) {
  __shared__ short As[128 * 64];
  __shared__ short Bs[128 * 64];
  const int tid = threadIdx.x;
  const int w = tid >> 6, l = tid & 63;
  const int lhi = l >> 4, llo = l & 15;
  // XCD swizzle: consecutive-id blocks (round-robin across 8 XCDs) -> contiguous tiles.
  const int nwg = gridDim.x * gridDim.y;
  int id = blockIdx.y * gridDim.x + blockIdx.x;
  id = (id & 7) * (nwg >> 3) + (id >> 3);
  const int tileM = (id / gridDim.x) * 128;
  const int tileN = (id % gridDim.x) * 128;
  const int wrow = (w >> 1) * 64, wcol = (w & 1) * 64;

  f32x4 zf = {0.f, 0.f, 0.f, 0.f};
  f32x4 acc[4][4];
#pragma unroll
  for (int i = 0; i < 4; ++i)
#pragma unroll
    for (int j = 0; j < 4; ++j) acc[i][j] = zf;

  for (int k0 = 0; k0 < K; k0 += 64) {
    __syncthreads();
#pragma unroll
    for (int i = 0; i < 4; ++i) {   // A: 16KB
      int F = (i * 4 + w) * 1024 + l * 16;
      int row = F >> 7, cs = (F & 127) >> 1;
      gload16(A + (size_t)(tileM + row) * K + k0 + cs, (char*)As + (i * 4 + w) * 1024);
    }
#pragma unroll
    for (int i = 0; i < 4; ++i) {   // B: 16KB
      int F = (i * 4 + w) * 1024 + l * 16;
      int row = F >> 7, cs = (F & 127) >> 1;
      int rn = tileN + row; if (rn >= N) rn = N - 1;
      gload16(Bm + (size_t)rn * K + k0 + cs, (char*)Bs + (i * 4 + w) * 1024);
    }
    asm volatile("s_waitcnt vmcnt(0)" ::: "memory");
    __syncthreads();
#pragma unroll
    for (int ks = 0; ks < 2; ++ks) {
      bf16x8 av[4], bv[4];
#pragma unroll
      for (int fm = 0; fm < 4; ++fm)
        av[fm] = *(const bf16x8*)&As[(wrow + fm * 16 + llo) * 64 + ks * 32 + lhi * 8];
#pragma unroll
      for (int fn = 0; fn < 4; ++fn)
        bv[fn] = *(const bf16x8*)&Bs[(wcol + fn * 16 + llo) * 64 + ks * 32 + lhi * 8];
#pragma unroll
      for (int fm = 0; fm < 4; ++fm)
#pragma unroll
        for (int fn = 0; fn < 4; ++fn)
          acc[fm][fn] = mfma16(av[fm], bv[fn], acc[fm][fn]);
    }
  }
#pragma unroll
  for (int fm = 0; fm < 4; ++fm)
#pragma unroll
    for (int fn = 0; fn < 4; ++fn) {
      int m = tileM + wrow + fm * 16 + lhi * 4;
      int n = tileN + wcol + fn * 16 + llo;
      if (n < N) {
        float bb = bias ? bias[n] : 0.f;
        f32x4 v = acc[fm][fn];
#pragma unroll
        for (int j = 0; j < 4; ++j) {
          float r = v[j] + bb;
          if (OB) ((short*)Cv)[(size_t)(m + j) * N + n] = f2bf(r);
          else    ((float*)Cv)[(size_t)(m + j) * N + n] = r;
        }
      }
    }
}

// ---------------- fused LSTM step: g = P[row(t)] + h@Wh'^T ; gates; masked update --------
// Wh' rows are gate-interleaved: j' = 4n + gate, so a 128-col tile = 32 n-values, all gates.
// grid (16, 1, zdim): z selects fwd/bwd pointer set (encoder) or set 0 (decoder).
__global__ void __launch_bounds__(256) lstm_step_k(
    const short* __restrict__ hbf0, const short* __restrict__ hbf1,
    const short* __restrict__ W0,  const short* __restrict__ W1,
    const short* __restrict__ P0,  const short* __restrict__ P1,
    const float* __restrict__ hp0, const float* __restrict__ hp1,
    float* __restrict__ hn0, float* __restrict__ hn1,
    short* __restrict__ hnb0, short* __restrict__ hnb1,
    float* __restrict__ c0p, float* __restrict__ c1p,
    short* __restrict__ ENCp, const int* __restrict__ lens,
    int t, int mode, float* __restrict__ cvh, short* __restrict__ cvhb) {
  __shared__ short As[64 * 64];     // h tile 64x64 bf16
  __shared__ short Bs[128 * 64];    // W tile 128x64 bf16
  __shared__ float gsm[64 * 128];   // pre-activation tile
  const int z = blockIdx.z;
  const short* hbf = z ? hbf1 : hbf0;
  const short* Wm  = z ? W1  : W0;
  const short* P   = z ? P1  : P0;
  const float* hp  = z ? hp1 : hp0;
  float* hn  = z ? hn1 : hn0;
  short* hnb = z ? hnb1 : hnb0;
  float* cst = z ? c1p : c0p;

  const int tid = threadIdx.x;
  const int w = tid >> 6, l = tid & 63;
  const int lhi = l >> 4, llo = l & 15;
  const int tileN = blockIdx.x * 128;

  f32x4 zf = {0.f, 0.f, 0.f, 0.f};
  f32x4 acc[4][2];
#pragma unroll
  for (int i = 0; i < 4; ++i) { acc[i][0] = zf; acc[i][1] = zf; }

  for (int k0 = 0; k0 < 512; k0 += 64) {
    __syncthreads();
#pragma unroll
    for (int i = 0; i < 2; ++i) {   // A: 8KB (64 rows)
      int F = (i * 4 + w) * 1024 + l * 16;
      int row = F >> 7, cs = (F & 127) >> 1;
      gload16(hbf + (size_t)row * 512 + k0 + cs, (char*)As + (i * 4 + w) * 1024);
    }
#pragma unroll
    for (int i = 0; i < 4; ++i) {   // B: 16KB
      int F = (i * 4 + w) * 1024 + l * 16;
      int row = F >> 7, cs = (F & 127) >> 1;
      gload16(Wm + (size_t)(tileN + row) * 512 + k0 + cs, (char*)Bs + (i * 4 + w) * 1024);
    }
    asm volatile("s_waitcnt vmcnt(0)" ::: "memory");
    __syncthreads();
#pragma unroll
    for (int ks = 0; ks < 2; ++ks) {
      bf16x8 av[4], bv[2];
#pragma unroll
      for (int fm = 0; fm < 4; ++fm)
        av[fm] = *(const bf16x8*)&As[(fm * 16 + llo) * 64 + ks * 32 + lhi * 8];
#pragma unroll
      for (int fn = 0; fn < 2; ++fn)
        bv[fn] = *(const bf16x8*)&Bs[(w * 32 + fn * 16 + llo) * 64 + ks * 32 + lhi * 8];
#pragma unroll
      for (int fm = 0; fm < 4; ++fm)
#pragma unroll
        for (int fn = 0; fn < 2; ++fn)
          acc[fm][fn] = mfma16(av[fm], bv[fn], acc[fm][fn]);
    }
  }
  // dump acc -> LDS (separate region; no hazard with As/Bs readers)
#pragma unroll
  for (int fm = 0; fm < 4; ++fm)
#pragma unroll
    for (int fn = 0; fn < 2; ++fn) {
      int r = fm * 16 + lhi * 4;
      int cc = w * 32 + fn * 16 + llo;
      f32x4 v = acc[fm][fn];
#pragma unroll
      for (int j = 0; j < 4; ++j) gsm[(r + j) * 128 + cc] = v[j];
    }
  __syncthreads();

  // elementwise: 64 b x 32 n per tile
  const int n0 = tileN >> 2;
  for (int it = tid; it < 2048; it += 256) {
    int b = it >> 5, nn = it & 31, n = n0 + nn;
    int len = lens[b];
    int prow;
    if (mode == 0) {
      if (z == 0) prow = t * 64 + b;
      else { int idx = len - 1 - t; if (idx < 0) idx = 0; prow = idx * 64 + b; }
    } else prow = t * 64 + b;
    f32x4 g4 = *(f32x4*)&gsm[b * 128 + nn * 4];
    short4v pv = *(const short4v*)(P + (size_t)prow * 2048 + tileN + nn * 4);
    float gi = sigm(g4.x + bf2f(pv.x));
    float gf = sigm(g4.y + bf2f(pv.y));
    float gg = tanhf(g4.z + bf2f(pv.z));
    float go = sigm(g4.w + bf2f(pv.w));
    float cold = cst[b * 512 + n];
    float c2 = gf * cold + gi * gg;
    float h2 = go * tanhf(c2);
    bool msk = (mode == 1) || (t < len);
    float hv = msk ? h2 : hp[b * 512 + n];
    hn[b * 512 + n] = hv;
    hnb[b * 512 + n] = f2bf(hv);
    if (msk) cst[b * 512 + n] = c2;
    if (mode == 0) {
      if (msk) {
        int row = z ? (len - 1 - t) : t;
        ENCp[((size_t)row * 64 + b) * 1024 + z * 512 + n] = f2bf(h2);
      }
    } else {
      size_t o = ((size_t)t * 64 + b) * 1536 + 1024 + n;
      cvh[o] = h2;
      cvhb[o] = f2bf(h2);
    }
  }
}

// ---------------- attention: per-batch block. q = h2@Wv^T+bV ; e ; softmax ; cvec --------
// ENC is bf16. e uses rows t'*64+b (t-major); cvec uses flat rows b*128+t' (the
// reference's reshape(B,T,2H) aliasing quirk).
__global__ void __launch_bounds__(256) attn_k(const float* __restrict__ cvh_in,
                                              const short* __restrict__ Wv,
                                              const float* __restrict__ bV,
                                              const short* __restrict__ ENC,
                                              float* __restrict__ cvh,
                                              short* __restrict__ cvhb, int t) {
  __shared__ float h2s[512];
  __shared__ float qs[1024];
  __shared__ float es[128];
  __shared__ float red[2];
  const int b = blockIdx.x, tid = threadIdx.x;
  const float* h2p = cvh_in + ((size_t)t * 64 + b) * 1536 + 1024;
  for (int k = tid; k < 512; k += 256) h2s[k] = h2p[k];
  __syncthreads();
  // query: 4 rows per thread
  float qa[4];
#pragma unroll
  for (int jj = 0; jj < 4; ++jj) qa[jj] = bV[tid + jj * 256];
  for (int k = 0; k < 512; k += 8) {
    float hv[8];
#pragma unroll
    for (int i = 0; i < 8; ++i) hv[i] = h2s[k + i];
#pragma unroll
    for (int jj = 0; jj < 4; ++jj) {
      bf16x8 wv = *(const bf16x8*)(Wv + (size_t)(tid + jj * 256) * 512 + k);
#pragma unroll
      for (int i = 0; i < 8; ++i) qa[jj] += hv[i] * bf2f(wv[i]);
    }
  }
#pragma unroll
  for (int jj = 0; jj < 4; ++jj) qs[tid + jj * 256] = qa[jj];
  __syncthreads();
  // e[t'] over enc rows t'*64+b
  if (tid < 128) {
    const short* er = ENC + ((size_t)tid * 64 + b) * 1024;
    float a0 = 0.f;
    for (int h = 0; h < 1024; h += 8) {
      bf16x8 ev = *(const bf16x8*)&er[h];
#pragma unroll
      for (int i = 0; i < 8; ++i) a0 += qs[h + i] * bf2f(ev[i]);
    }
    es[tid] = a0;
  }
  __syncthreads();
  if (tid < 64) {
    float m = fmaxf(es[tid], es[tid + 64]);
#pragma unroll
    for (int off = 32; off; off >>= 1) m = fmaxf(m, __shfl_xor(m, off));
    if (tid == 0) red[0] = m;
  }
  __syncthreads();
  float mx = red[0];
  if (tid < 128) es[tid] = expf(es[tid] - mx);
  __syncthreads();
  if (tid < 64) {
    float s = es[tid] + es[tid + 64];
#pragma unroll
    for (int off = 32; off; off >>= 1) s += __shfl_xor(s, off);
    if (tid == 0) red[1] = s;
  }
  __syncthreads();
  float rs = 1.f / red[1];
  // cvec over flat rows b*128+t'
  int h0 = tid * 4;
  f32x4 acc = {0.f, 0.f, 0.f, 0.f};
  const short* cr = ENC + ((size_t)b * 128) * 1024 + h0;
  for (int tp = 0; tp < 128; ++tp) {
    float p = es[tp];
    short4v ev = *(const short4v*)(cr + (size_t)tp * 1024);
    acc.x += p * bf2f(ev.x); acc.y += p * bf2f(ev.y);
    acc.z += p * bf2f(ev.z); acc.w += p * bf2f(ev.w);
  }
  acc.x *= rs; acc.y *= rs; acc.z *= rs; acc.w *= rs;
  size_t o = ((size_t)t * 64 + b) * 1536 + h0;
  float* dst = cvh + o;
  dst[0] = acc.x; dst[1] = acc.y; dst[2] = acc.z; dst[3] = acc.w;
  short* db = cvhb + o;
  db[0] = f2bf(acc.x); db[1] = f2bf(acc.y); db[2] = f2bf(acc.z); db[3] = f2bf(acc.w);
}

// ---------------- decoder init: h0/c0 = [sf|sb] @ W^T + b (fp32, no nonlinearity) --------
__global__ void __launch_bounds__(256) dec_init_k(
    const float* __restrict__ hf, const float* __restrict__ hb,
    const float* __restrict__ cf, const float* __restrict__ cb,
    const float* __restrict__ Wrh, const float* __restrict__ brh,
    const float* __restrict__ Wrc, const float* __restrict__ brc,
    float* __restrict__ h0f, short* __restrict__ h0b, float* __restrict__ c0) {
  int which = blockIdx.x >> 6;
  int n0 = (blockIdx.x & 63) * 8;
  const float* W  = which ? Wrc : Wrh;
  const float* bs = which ? brc : brh;
  const float* xa = which ? cf : hf;
  const float* xb = which ? cb : hb;
  for (int it = threadIdx.x; it < 512; it += 256) {
    int b = it >> 3, n = n0 + (it & 7);
    const float* wr = W + (size_t)n * 1024;
    const float* va = xa + b * 512;
    const float* vb = xb + b * 512;
    float a0 = bs[n];
#pragma unroll 4
    for (int k = 0; k < 512; ++k) a0 += va[k] * wr[k] + vb[k] * wr[512 + k];
    if (which == 0) { h0f[b * 512 + n] = a0; h0b[b * 512 + n] = f2bf(a0); }
    else c0[b * 512 + n] = a0;
  }
}

// ---------------- conversions / gathers -------------------------------------------------
// gate-interleaved shuffle-convert: out'[4n+g][k] = bf16(in[g*512+n][k])
__global__ void __launch_bounds__(256) shufw_k(const float* __restrict__ in,
                                               short* __restrict__ out, int K) {
  int jp = blockIdx.x, n = jp >> 2, g = jp & 3;
  const float* src = in + (size_t)(g * 512 + n) * K;
  short* dst = out + (size_t)jp * K;
  for (int k = threadIdx.x; k < K; k += 256) dst[k] = f2bf(src[k]);
}
__global__ void __launch_bounds__(256) shufb_k(const float* bf, const float* bb, const float* bd,
                                               float* of, float* ob, float* od) {
  int i = blockIdx.x * 256 + threadIdx.x;  // 0..2047
  int n = i >> 2, g = i & 3, j = g * 512 + n;
  of[i] = bf[j]; ob[i] = bb[j]; od[i] = bd[j];
}
__global__ void __launch_bounds__(256) convw_k(const float* __restrict__ in,
                                               short* __restrict__ out, long n4) {
  long i = (long)blockIdx.x * 256 + threadIdx.x;
  long stride = (long)gridDim.x * 256;
  for (; i < n4; i += stride) {
    f32x4 v = ((const f32x4*)in)[i];
    short* d = out + i * 4;
    d[0] = f2bf(v.x); d[1] = f2bf(v.y); d[2] = f2bf(v.z); d[3] = f2bf(v.w);
  }
}
// mode 0: Ex rows (t*64+b), tok = x[b*128+t]; mode 1: DecEmb, tok = t ? y[b*64+t-1] : SOS(1)
__global__ void __launch_bounds__(256) gather_k(const float* __restrict__ emb,
                                                const int* __restrict__ toks,
                                                short* __restrict__ out, int mode) {
  int r = blockIdx.x * 4 + (threadIdx.x >> 6);
  int lane = threadIdx.x & 63;
  int t = r >> 6, b = r & 63;
  int tok = mode ? (t ? toks[b * 64 + t - 1] : 1) : toks[b * 128 + t];
  const float* src = emb + (size_t)tok * 256 + lane * 4;
  short* dst = out + (size_t)r * 256 + lane * 4;
  f32x4 v = *(const f32x4*)src;
  dst[0] = f2bf(v.x); dst[1] = f2bf(v.y); dst[2] = f2bf(v.z); dst[3] = f2bf(v.w);
}

// ---------------- host ------------------------------------------------------------------
extern "C" void kernel_launch(void* const* d_in, const int* in_sizes, int n_in,
                              void* d_out, int out_size, void* d_ws, size_t ws_size,
                              hipStream_t stream) {
  const int*   x      = (const int*)d_in[0];
  const int*   lens   = (const int*)d_in[1];
  const int*   y      = (const int*)d_in[2];
  const float* emb_in = (const float*)d_in[4];
  const float* emb_out= (const float*)d_in[5];
  const float* W_ih_f = (const float*)d_in[6];
  const float* W_hh_f = (const float*)d_in[7];
  const float* b_f    = (const float*)d_in[8];
  const float* W_ih_b = (const float*)d_in[9];
  const float* W_hh_b = (const float*)d_in[10];
  const float* b_b    = (const float*)d_in[11];
  const float* W_rh   = (const float*)d_in[12];
  const float* b_rh   = (const float*)d_in[13];
  const float* W_rc   = (const float*)d_in[14];
  const float* b_rc   = (const float*)d_in[15];
  const float* W_ih_d = (const float*)d_in[16];
  const float* W_hh_d = (const float*)d_in[17];
  const float* b_d    = (const float*)d_in[18];
  const float* W_V    = (const float*)d_in[19];
  const float* b_V    = (const float*)d_in[20];
  const float* W_fc   = (const float*)d_in[21];
  const float* b_fc   = (const float*)d_in[22];
  float* out = (float*)d_out;

  char* base = (char*)d_ws;
  size_t off = 0;
  auto carve = [&](size_t bytes) -> void* {
    void* r = base + off; off += (bytes + 255) & ~(size_t)255; return r;
  };
  short* Ex     = (short*)carve((size_t)T_ * B_ * E_ * 2);
  short* DecEmb = (short*)carve((size_t)OUT_ * B_ * E_ * 2);
  short* Wihf   = (short*)carve((size_t)G4_ * E_ * 2);
  short* Wihb   = (short*)carve((size_t)G4_ * E_ * 2);
  short* Wihd   = (short*)carve((size_t)G4_ * E_ * 2);
  short* Whhf   = (short*)carve((size_t)G4_ * H_ * 2);
  short* Whhb   = (short*)carve((size_t)G4_ * H_ * 2);
  short* Whhd   = (short*)carve((size_t)G4_ * H_ * 2);
  float* bqf    = (float*)carve((size_t)G4_ * 4);
  float* bqb    = (float*)carve((size_t)G4_ * 4);
  float* bqd    = (float*)carve((size_t)G4_ * 4);
  short* Wv     = (short*)carve((size_t)H2_ * H_ * 2);
  short* Wfc    = (short*)carve((size_t)V_ * CAT_ * 2);
  short* Pf     = (short*)carve((size_t)T_ * B_ * G4_ * 2);   // bf16
  short* Pb     = (short*)carve((size_t)T_ * B_ * G4_ * 2);   // bf16
  short* Pd     = (short*)carve((size_t)OUT_ * B_ * G4_ * 2); // bf16
  short* ENC    = (short*)carve((size_t)T_ * B_ * H2_ * 2);   // bf16
  float* cvh    = (float*)carve((size_t)OUT_ * B_ * CAT_ * 4);
  short* cvhb   = (short*)carve((size_t)OUT_ * B_ * CAT_ * 2);
  // zero block (contiguous, all sizes multiple of 256B)
  float* hf_f0  = (float*)carve((size_t)B_ * H_ * 4);
  float* hf_b0  = (float*)carve((size_t)B_ * H_ * 4);
  float* cF     = (float*)carve((size_t)B_ * H_ * 4);
  float* cB     = (float*)carve((size_t)B_ * H_ * 4);
  short* hbf_f0 = (short*)carve((size_t)B_ * H_ * 2);
  short* hbf_b0 = (short*)carve((size_t)B_ * H_ * 2);
  size_t zbytes = (size_t)(base + off - (char*)hf_f0);
  float* hf_f1  = (float*)carve((size_t)B_ * H_ * 4);
  float* hf_b1  = (float*)carve((size_t)B_ * H_ * 4);
  short* hbf_f1 = (short*)carve((size_t)B_ * H_ * 2);
  short* hbf_b1 = (short*)carve((size_t)B_ * H_ * 2);
  float* hf_d0  = (float*)carve((size_t)B_ * H_ * 4);
  float* hf_d1  = (float*)carve((size_t)B_ * H_ * 4);
  short* hbf_d0 = (short*)carve((size_t)B_ * H_ * 2);
  short* hbf_d1 = (short*)carve((size_t)B_ * H_ * 2);
  float* cD     = (float*)carve((size_t)B_ * H_ * 4);
  if (off > ws_size) return;  // workspace too small: bail (visible as validation failure)

  // init
  hipMemsetAsync(ENC, 0, (size_t)T_ * B_ * H2_ * 2, stream);
  hipMemsetAsync(hf_f0, 0, zbytes, stream);

  // weight conversion / shuffles
  shufw_k<<<2048, 256, 0, stream>>>(W_ih_f, Wihf, E_);
  shufw_k<<<2048, 256, 0, stream>>>(W_ih_b, Wihb, E_);
  shufw_k<<<2048, 256, 0, stream>>>(W_ih_d, Wihd, E_);
  shufw_k<<<2048, 256, 0, stream>>>(W_hh_f, Whhf, H_);
  shufw_k<<<2048, 256, 0, stream>>>(W_hh_b, Whhb, H_);
  shufw_k<<<2048, 256, 0, stream>>>(W_hh_d, Whhd, H_);
  shufb_k<<<8, 256, 0, stream>>>(b_f, b_b, b_d, bqf, bqb, bqd);
  convw_k<<<512, 256, 0, stream>>>(W_V, Wv, (long)H2_ * H_ / 4);
  convw_k<<<4096, 256, 0, stream>>>(W_fc, Wfc, (long)V_ * CAT_ / 4);
  gather_k<<<2048, 256, 0, stream>>>(emb_in, x, Ex, 0);
  gather_k<<<1024, 256, 0, stream>>>(emb_out, y, DecEmb, 1);

  // input projections (bias folded), bf16 output
  gemm_k<true><<<dim3(16, 64), 256, 0, stream>>>(Ex, Wihf, Pf, bqf, G4_, E_);
  gemm_k<true><<<dim3(16, 64), 256, 0, stream>>>(Ex, Wihb, Pb, bqb, G4_, E_);
  gemm_k<true><<<dim3(16, 32), 256, 0, stream>>>(DecEmb, Wihd, Pd, bqd, G4_, E_);

  // encoder (fwd+bwd batched via z)
  float* hff[2] = {hf_f0, hf_f1};  float* hfb[2] = {hf_b0, hf_b1};
  short* hbff[2] = {hbf_f0, hbf_f1}; short* hbfb[2] = {hbf_b0, hbf_b1};
  for (int t = 0; t < T_; ++t) {
    int a = t & 1, b2 = a ^ 1;
    lstm_step_k<<<dim3(16, 1, 2), 256, 0, stream>>>(
        hbff[a], hbfb[a], Whhf, Whhb, Pf, Pb,
        hff[a], hfb[a], hff[b2], hfb[b2], hbff[b2], hbfb[b2], cF, cB,
        ENC, lens, t, 0, nullptr, nullptr);
  }

  dec_init_k<<<128, 256, 0, stream>>>(hf_f0, hf_b0, cF, cB, W_rh, b_rh, W_rc, b_rc,
                                      hf_d0, hbf_d0, cD);

  // decoder
  float* hfd[2] = {hf_d0, hf_d1}; short* hbfd[2] = {hbf_d0, hbf_d1};
  for (int t = 0; t < OUT_; ++t) {
    int a = t & 1, b2 = a ^ 1;
    lstm_step_k<<<dim3(16, 1, 1), 256, 0, stream>>>(
        hbfd[a], nullptr, Whhd, nullptr, Pd, nullptr,
        hfd[a], nullptr, hfd[b2], nullptr, hbfd[b2], nullptr, cD, nullptr,
        nullptr, lens, t, 1, cvh, cvhb);
    attn_k<<<64, 256, 0, stream>>>(cvh, Wv, b_V, ENC, cvh, cvhb, t);
  }

  // final FC: (4096 x 1536) @ (20000 x 1536)^T + b_fc -> d_out (fp32)
  gemm_k<false><<<dim3(157, 32), 256, 0, stream>>>(cvhb, Wfc, out, b_fc, V_, CAT_);
}